// Round 14
// baseline (45.177 us; speedup 1.0000x reference)
//
#include <hip/hip_runtime.h>
#include <math.h>

#define KPOOL 16
#define SPLIT 8            // threads per graph
#define GPB 8              // graphs per 64-thread (single-wave) block
#define CAP 3072           // staged floats per block (12 KB); need ~2056, 22 sigma

typedef float f32x4 __attribute__((ext_vector_type(4)));

__device__ __forceinline__ void ce(float& x, float& y) {
  float hi = fmaxf(x, y), lo = fminf(x, y);
  x = hi;
  y = lo;
}

// Batcher odd-even mergesort, 8 inputs, 19 CEs, descending.
__device__ __forceinline__ void sort8(float (&v)[8]) {
  ce(v[0], v[1]); ce(v[2], v[3]); ce(v[4], v[5]); ce(v[6], v[7]);
  ce(v[0], v[2]); ce(v[1], v[3]); ce(v[4], v[6]); ce(v[5], v[7]);
  ce(v[1], v[2]); ce(v[5], v[6]);
  ce(v[0], v[4]); ce(v[1], v[5]); ce(v[2], v[6]); ce(v[3], v[7]);
  ce(v[2], v[4]); ce(v[3], v[5]);
  ce(v[1], v[2]); ce(v[3], v[4]); ce(v[5], v[6]);
}

// t sorted-16 desc, b sorted-8 desc -> t = top-16 of union, sorted.
__device__ __forceinline__ void merge8into16(float (&t)[KPOOL], const float (&b)[8]) {
#pragma unroll
  for (int i = 8; i < 16; ++i) t[i] = fmaxf(t[i], b[15 - i]);
#pragma unroll
  for (int s = 8; s >= 1; s >>= 1) {
#pragma unroll
    for (int i = 0; i < 16; ++i)
      if ((i & s) == 0) ce(t[i], t[i + s]);
  }
}

// Merge this lane's sorted-16 with lane^dist's: top-16 of union.
__device__ __forceinline__ void merge_partner(float (&t)[KPOOL], int dist) {
  float c[KPOOL];
#pragma unroll
  for (int i = 0; i < KPOOL; ++i) {
    float o = __shfl_xor(t[KPOOL - 1 - i], dist);
    c[i] = fmaxf(t[i], o);
  }
#pragma unroll
  for (int s = 8; s >= 1; s >>= 1) {
#pragma unroll
    for (int i = 0; i < KPOOL; ++i)
      if ((i & s) == 0) ce(c[i], c[i + s]);
  }
#pragma unroll
  for (int i = 0; i < KPOOL; ++i) t[i] = c[i];
}

__device__ __forceinline__ int lb_range(const int* __restrict__ a, int lo,
                                        int hi, int key) {
  while (lo < hi) {
    int mid = (lo + hi) >> 1;
    if (a[mid] < key) lo = mid + 1;
    else hi = mid;
  }
  return lo;
}

// Exact lower_bound via batched 8-ary search (7 independent probes/round over
// a +-16384 = 8-sigma verified window; full-range fallback for exactness).
__global__ __launch_bounds__(256)
void boundary_kernel(const int* __restrict__ emap, int total, int n,
                     int* __restrict__ starts, float* __restrict__ wn_out,
                     const float* __restrict__ W) {
  const int g = blockIdx.x * 256 + threadIdx.x;
  if (g == 0) {  // softmax(W), grid-uniform
    float w[KPOOL], m = -INFINITY, s = 0.0f;
#pragma unroll
    for (int k = 0; k < KPOOL; ++k) { w[k] = W[k]; m = fmaxf(m, w[k]); }
#pragma unroll
    for (int k = 0; k < KPOOL; ++k) { w[k] = expf(w[k] - m); s += w[k]; }
#pragma unroll
    for (int k = 0; k < KPOOL; ++k) wn_out[k] = w[k] / s;
  }
  if (g > n) return;
  if (g == 0) { starts[0] = 0; return; }       // e_map values >= 0
  if (g >= n) { starts[n] = total; return; }   // e_map values < n

  const int key = g;
  const int W0 = 32768;
  if (total < W0) { starts[g] = lb_range(emap, 0, total, key); return; }

  long long E = (long long)key * total / n;
  int wlo = (int)(E - W0 / 2);
  if (wlo < 0) wlo = 0;
  if (wlo > total - W0) wlo = total - W0;

  int p[7];
#pragma unroll
  for (int k = 0; k < 7; ++k) p[k] = emap[wlo + (k + 1) * 4096];
  const int vlo = (wlo > 0) ? emap[wlo - 1] : key - 1 - key;  // force "< key"
  const int vhi = emap[wlo + W0 - 1];
  const bool ok = (vlo < key) && ((wlo + W0 == total) || (vhi >= key));
  if (!ok) { starts[g] = lb_range(emap, 0, total, key); return; }

  int lo = wlo;
  int c = 0;
#pragma unroll
  for (int k = 0; k < 7; ++k) c += (p[k] < key) ? 1 : 0;
  lo += c * 4096;

#pragma unroll
  for (int w8 = 512; w8 >= 1; w8 >>= 3) {
#pragma unroll
    for (int k = 0; k < 7; ++k) p[k] = emap[lo + (k + 1) * w8];
    c = 0;
#pragma unroll
    for (int k = 0; k < 7; ++k) c += (p[k] < key) ? 1 : 0;
    lo += c * w8;
  }
  starts[g] = (emap[lo] < key) ? lo + 1 : lo;
}

// Single-wave block, 8 graphs: stage the block's contiguous Y-range into LDS
// via async global_load_lds with the LINEAR lane-order layout the hardware
// mandates (dest == uniform base + lane*16B; R12-proven). __syncthreads on a
// 1-wave block is a private vmcnt drain -> no cross-wave convoy; ~13 staggered
// blocks/CU overlap staging with compute.
__global__ __launch_bounds__(64)
void sortpool_lds(const float* __restrict__ Y,
                  const int* __restrict__ starts,
                  const float* __restrict__ Wn,
                  float* __restrict__ out, int total, int n) {
  __shared__ float buf[CAP];
  const int tid = threadIdx.x;           // 0..63
  const int j = tid >> 3;                // graph slot in block (0..7)
  const int q = tid & 7;                 // stride id within graph
  const int g0 = blockIdx.x * GPB;
  if (g0 >= n) return;                   // block-uniform
  const int gend = (g0 + GPB < n) ? g0 + GPB : n;
  const int g = g0 + j;
  const bool valid = (g < gend);

  const int base = starts[g0] & ~7;      // 32B-aligned stage origin
  const int end = starts[gend];
  int staged = (end - base + 3) & ~3;    // pad to 16B loads
  const int lim = total - base;          // both 8/4-aligned
  if (staged > CAP) staged = CAP;
  if (staged > lim) staged = lim;

  // ---- async stage: lane l writes buf + l*16B + trip*1024B (linear = HW map)
  for (int off = tid * 4; off < staged; off += 256) {
    __builtin_amdgcn_global_load_lds(
        (const __attribute__((address_space(1))) void*)(Y + base + off),
        (__attribute__((address_space(3))) void*)(buf + off), 16, 0, 0);
  }
  __syncthreads();  // 1-wave block: private vmcnt(0), near-free

  if (valid) {
    const int s0 = starts[g];
    const int s1 = starts[g + 1];

    float t[KPOOL];
#pragma unroll
    for (int i = 0; i < KPOOL; ++i) t[i] = -INFINITY;

    const int B0 = s0 >> 3;
    const int B1 = (s1 + 7) >> 3;
#pragma unroll 1
    for (int b = B0 + q; b < B1; b += SPLIT) {
      const int off = (b << 3) - base;   // >= 0; 32B-aligned
      float v[8];
      if (off + 8 <= staged) {           // normal path: LDS
        const f32x4* p = reinterpret_cast<const f32x4*>(buf + off);
        const f32x4 a = p[0], c2 = p[1];
        v[0] = a[0]; v[1] = a[1]; v[2] = a[2]; v[3] = a[3];
        v[4] = c2[0]; v[5] = c2[1]; v[6] = c2[2]; v[7] = c2[3];
      } else {  // rare: CAP overflow -> direct global loads (exact)
#pragma unroll
        for (int jj = 0; jj < 8; ++jj) {
          const int idx = (b << 3) + jj;
          v[jj] = (idx < total) ? Y[idx] : -INFINITY;
        }
      }
      const int bbase = b << 3;
      if (bbase < s0 || bbase + 8 > s1) {  // only first/last block partial
#pragma unroll
        for (int jj = 0; jj < 8; ++jj) {
          const int idx = bbase + jj;
          if (idx < s0 || idx >= s1) v[jj] = -INFINITY;
        }
      }
      sort8(v);
      merge8into16(t, v);
    }

    // combine the 8 strides' sorted-16 lists (butterfly within 8 lanes)
    merge_partner(t, 1);
    merge_partner(t, 2);
    merge_partner(t, 4);

    // weighted sum with precomputed softmax(W); -inf (exhausted) -> 0
    float res = 0.0f;
#pragma unroll
    for (int k = 0; k < KPOOL; ++k) {
      const float tv = t[k];
      res += (tv > -INFINITY) ? tv * Wn[k] : 0.0f;
    }
    if (q == 0) out[g] = res;
  }
}

// Fallback main (no workspace): per-thread full binary search, global scan.
__global__ __launch_bounds__(256, 4)
void sortpool_main_nows(const float* __restrict__ Y, const float* __restrict__ W,
                        const int* __restrict__ emap, float* __restrict__ out,
                        int total, int n) {
  const int tid = blockIdx.x * 256 + threadIdx.x;
  const int g = tid >> 3;
  const int q = tid & 7;
  if (g >= n) return;
  const int s0 = lb_range(emap, 0, total, g);
  const int s1 = lb_range(emap, 0, total, g + 1);
  float t[KPOOL];
#pragma unroll
  for (int i = 0; i < KPOOL; ++i) t[i] = -INFINITY;
  const int B0 = s0 >> 3;
  const int B1 = (s1 + 7) >> 3;
#pragma unroll 1
  for (int b = B0 + q; b < B1; b += SPLIT) {
    float v[8];
#pragma unroll
    for (int jj = 0; jj < 8; ++jj) {
      const int idx = (b << 3) + jj;
      v[jj] = (idx < total && idx >= s0 && idx < s1) ? Y[idx] : -INFINITY;
    }
    sort8(v);
    merge8into16(t, v);
  }
  merge_partner(t, 1);
  merge_partner(t, 2);
  merge_partner(t, 4);
  float wv[KPOOL], m = -INFINITY, s = 0.0f;
#pragma unroll
  for (int k = 0; k < KPOOL; ++k) { wv[k] = W[k]; m = fmaxf(m, wv[k]); }
#pragma unroll
  for (int k = 0; k < KPOOL; ++k) { wv[k] = expf(wv[k] - m); s += wv[k]; }
  const float inv = 1.0f / s;
  float res = 0.0f;
#pragma unroll
  for (int k = 0; k < KPOOL; ++k) {
    const float tv = t[k];
    res += (tv > -INFINITY) ? tv * (wv[k] * inv) : 0.0f;
  }
  if (q == 0) out[g] = res;
}

extern "C" void kernel_launch(void* const* d_in, const int* in_sizes, int n_in,
                              void* d_out, int out_size, void* d_ws, size_t ws_size,
                              hipStream_t stream) {
  const float* Y = (const float*)d_in[0];   // [TOTAL]
  const float* W = (const float*)d_in[1];   // [16]
  const int* emap = (const int*)d_in[2];    // [TOTAL], sorted
  const int total = in_sizes[0];
  const int n = in_sizes[3];                // len(v_count)
  float* out = (float*)d_out;               // [N] float32

  int* starts = (int*)d_ws;
  float* wn_buf = (float*)((char*)d_ws + (size_t)(n + 1) * sizeof(int));
  const bool use_ws =
      (ws_size >= (size_t)(n + 1) * sizeof(int) + KPOOL * sizeof(float));

  if (use_ws) {
    const int nb = (n + 1 + 255) / 256;
    boundary_kernel<<<nb, 256, 0, stream>>>(emap, total, n, starts, wn_buf, W);
    const int blocks = (n + GPB - 1) / GPB;
    sortpool_lds<<<blocks, 64, 0, stream>>>(Y, starts, wn_buf, out, total, n);
  } else {
    long long threads = (long long)n * SPLIT;
    const int blocks = (int)((threads + 255) / 256);
    sortpool_main_nows<<<blocks, 256, 0, stream>>>(Y, W, emap, out, total, n);
  }
}

// Round 15
// 42.183 us; speedup vs baseline: 1.0710x; 1.0710x over previous
//
#include <hip/hip_runtime.h>
#include <math.h>

#define KPOOL 16
#define SPLIT 8            // threads per graph
#define GPW 8              // graphs per wave
#define WPB 4              // waves per block (256 threads)
#define CAPW 2560          // staged floats per wave (10 KB); need ~2056 mean

typedef float f32x4 __attribute__((ext_vector_type(4)));

__device__ __forceinline__ void ce(float& x, float& y) {
  float hi = fmaxf(x, y), lo = fminf(x, y);
  x = hi;
  y = lo;
}

// Batcher odd-even mergesort, 8 inputs, 19 CEs, descending.
__device__ __forceinline__ void sort8(float (&v)[8]) {
  ce(v[0], v[1]); ce(v[2], v[3]); ce(v[4], v[5]); ce(v[6], v[7]);
  ce(v[0], v[2]); ce(v[1], v[3]); ce(v[4], v[6]); ce(v[5], v[7]);
  ce(v[1], v[2]); ce(v[5], v[6]);
  ce(v[0], v[4]); ce(v[1], v[5]); ce(v[2], v[6]); ce(v[3], v[7]);
  ce(v[2], v[4]); ce(v[3], v[5]);
  ce(v[1], v[2]); ce(v[3], v[4]); ce(v[5], v[6]);
}

// t sorted-16 desc, b sorted-8 desc -> t = top-16 of union, sorted.
__device__ __forceinline__ void merge8into16(float (&t)[KPOOL], const float (&b)[8]) {
#pragma unroll
  for (int i = 8; i < 16; ++i) t[i] = fmaxf(t[i], b[15 - i]);
#pragma unroll
  for (int s = 8; s >= 1; s >>= 1) {
#pragma unroll
    for (int i = 0; i < 16; ++i)
      if ((i & s) == 0) ce(t[i], t[i + s]);
  }
}

// Merge this lane's sorted-16 with lane^dist's: top-16 of union.
__device__ __forceinline__ void merge_partner(float (&t)[KPOOL], int dist) {
  float c[KPOOL];
#pragma unroll
  for (int i = 0; i < KPOOL; ++i) {
    float o = __shfl_xor(t[KPOOL - 1 - i], dist);
    c[i] = fmaxf(t[i], o);
  }
#pragma unroll
  for (int s = 8; s >= 1; s >>= 1) {
#pragma unroll
    for (int i = 0; i < KPOOL; ++i)
      if ((i & s) == 0) ce(c[i], c[i + s]);
  }
#pragma unroll
  for (int i = 0; i < KPOOL; ++i) t[i] = c[i];
}

__device__ __forceinline__ int lb_range(const int* __restrict__ a, int lo,
                                        int hi, int key) {
  while (lo < hi) {
    int mid = (lo + hi) >> 1;
    if (a[mid] < key) lo = mid + 1;
    else hi = mid;
  }
  return lo;
}

// Exact lower_bound via batched 8-ary search (7 independent probes/round over
// a +-16384 = 8-sigma verified window; full-range fallback for exactness).
__global__ __launch_bounds__(256)
void boundary_kernel(const int* __restrict__ emap, int total, int n,
                     int* __restrict__ starts, float* __restrict__ wn_out,
                     const float* __restrict__ W) {
  const int g = blockIdx.x * 256 + threadIdx.x;
  if (g == 0) {  // softmax(W), grid-uniform
    float w[KPOOL], m = -INFINITY, s = 0.0f;
#pragma unroll
    for (int k = 0; k < KPOOL; ++k) { w[k] = W[k]; m = fmaxf(m, w[k]); }
#pragma unroll
    for (int k = 0; k < KPOOL; ++k) { w[k] = expf(w[k] - m); s += w[k]; }
#pragma unroll
    for (int k = 0; k < KPOOL; ++k) wn_out[k] = w[k] / s;
  }
  if (g > n) return;
  if (g == 0) { starts[0] = 0; return; }       // e_map values >= 0
  if (g >= n) { starts[n] = total; return; }   // e_map values < n

  const int key = g;
  const int W0 = 32768;
  if (total < W0) { starts[g] = lb_range(emap, 0, total, key); return; }

  long long E = (long long)key * total / n;
  int wlo = (int)(E - W0 / 2);
  if (wlo < 0) wlo = 0;
  if (wlo > total - W0) wlo = total - W0;

  int p[7];
#pragma unroll
  for (int k = 0; k < 7; ++k) p[k] = emap[wlo + (k + 1) * 4096];
  const int vlo = (wlo > 0) ? emap[wlo - 1] : key - 1 - key;  // force "< key"
  const int vhi = emap[wlo + W0 - 1];
  const bool ok = (vlo < key) && ((wlo + W0 == total) || (vhi >= key));
  if (!ok) { starts[g] = lb_range(emap, 0, total, key); return; }

  int lo = wlo;
  int c = 0;
#pragma unroll
  for (int k = 0; k < 7; ++k) c += (p[k] < key) ? 1 : 0;
  lo += c * 4096;

#pragma unroll
  for (int w8 = 512; w8 >= 1; w8 >>= 3) {
#pragma unroll
    for (int k = 0; k < 7; ++k) p[k] = emap[lo + (k + 1) * w8];
    c = 0;
#pragma unroll
    for (int k = 0; k < 7; ++k) c += (p[k] < key) ? 1 : 0;
    lo += c * w8;
  }
  starts[g] = (emap[lo] < key) ? lo + 1 : lo;
}

// 256-thread block = 4 INDEPENDENT waves; each wave stages its own 8 graphs
// into its own LDS quarter (linear lane-order dest, HW-mandated) and drains
// with a wave-private vmcnt(0). No __syncthreads -> no cross-wave convoy;
// 16 waves/CU drain/compute staggered.
__global__ __launch_bounds__(256, 4)
void sortpool_lds(const float* __restrict__ Y,
                  const int* __restrict__ starts,
                  const float* __restrict__ Wn,
                  float* __restrict__ out, int total, int n) {
  __shared__ float buf[WPB * CAPW];
  const int w = threadIdx.x >> 6;        // wave id in block
  const int l = threadIdx.x & 63;        // lane
  const int j = l >> 3;                  // graph slot within wave (0..7)
  const int q = l & 7;                   // stride id within graph
  const int gw0 = (blockIdx.x * WPB + w) * GPW;  // wave's first graph
  if (gw0 >= n) return;                  // wave-uniform exit
  const int gend = (gw0 + GPW < n) ? gw0 + GPW : n;
  const int g = gw0 + j;
  const bool valid = (g < gend);

  const int sb = starts[gw0] & ~7;       // 32B-aligned stage origin
  const int end = starts[gend];
  int staged = (end - sb + 3) & ~3;      // pad to 16B loads
  const int lim = total - sb;            // sb 8-aligned, total 8-aligned
  if (staged > CAPW) staged = CAPW;
  if (staged > lim) staged = lim;

  float* wbuf = buf + w * CAPW;
  // ---- async stage: lane l writes wbuf + l*16B + trip*1024B (linear = HW map)
  for (int off = l * 4; off < staged; off += 256) {
    __builtin_amdgcn_global_load_lds(
        (const __attribute__((address_space(1))) void*)(Y + sb + off),
        (__attribute__((address_space(3))) void*)(wbuf + off), 16, 0, 0);
  }
  // wave-private drain (no block barrier). ds_reads below are memory ops, so
  // the "memory" clobber orders them; sched_barrier stops any hoisting.
  asm volatile("s_waitcnt vmcnt(0)" ::: "memory");
  __builtin_amdgcn_sched_barrier(0);

  if (valid) {
    const int s0 = starts[g];
    const int s1 = starts[g + 1];

    float t[KPOOL];
#pragma unroll
    for (int i = 0; i < KPOOL; ++i) t[i] = -INFINITY;

    const int B0 = s0 >> 3;
    const int B1 = (s1 + 7) >> 3;
#pragma unroll 1
    for (int b = B0 + q; b < B1; b += SPLIT) {
      const int off = (b << 3) - sb;     // >= 0; 32B-aligned
      float v[8];
      if (off + 8 <= staged) {           // normal path: LDS
        const f32x4* p = reinterpret_cast<const f32x4*>(wbuf + off);
        const f32x4 a = p[0], c2 = p[1];
        v[0] = a[0]; v[1] = a[1]; v[2] = a[2]; v[3] = a[3];
        v[4] = c2[0]; v[5] = c2[1]; v[6] = c2[2]; v[7] = c2[3];
      } else {  // rare: CAPW overflow -> direct global loads (exact)
#pragma unroll
        for (int jj = 0; jj < 8; ++jj) {
          const int idx = (b << 3) + jj;
          v[jj] = (idx < total) ? Y[idx] : -INFINITY;
        }
      }
      const int bbase = b << 3;
      if (bbase < s0 || bbase + 8 > s1) {  // only first/last block partial
#pragma unroll
        for (int jj = 0; jj < 8; ++jj) {
          const int idx = bbase + jj;
          if (idx < s0 || idx >= s1) v[jj] = -INFINITY;
        }
      }
      sort8(v);
      merge8into16(t, v);
    }

    // combine the 8 strides' sorted-16 lists (butterfly within 8 lanes)
    merge_partner(t, 1);
    merge_partner(t, 2);
    merge_partner(t, 4);

    // weighted sum with precomputed softmax(W); -inf (exhausted) -> 0
    float res = 0.0f;
#pragma unroll
    for (int k = 0; k < KPOOL; ++k) {
      const float tv = t[k];
      res += (tv > -INFINITY) ? tv * Wn[k] : 0.0f;
    }
    if (q == 0) out[g] = res;
  }
}

// Fallback main (no workspace): per-thread full binary search, global scan.
__global__ __launch_bounds__(256, 4)
void sortpool_main_nows(const float* __restrict__ Y, const float* __restrict__ W,
                        const int* __restrict__ emap, float* __restrict__ out,
                        int total, int n) {
  const int tid = blockIdx.x * 256 + threadIdx.x;
  const int g = tid >> 3;
  const int q = tid & 7;
  if (g >= n) return;
  const int s0 = lb_range(emap, 0, total, g);
  const int s1 = lb_range(emap, 0, total, g + 1);
  float t[KPOOL];
#pragma unroll
  for (int i = 0; i < KPOOL; ++i) t[i] = -INFINITY;
  const int B0 = s0 >> 3;
  const int B1 = (s1 + 7) >> 3;
#pragma unroll 1
  for (int b = B0 + q; b < B1; b += SPLIT) {
    float v[8];
#pragma unroll
    for (int jj = 0; jj < 8; ++jj) {
      const int idx = (b << 3) + jj;
      v[jj] = (idx < total && idx >= s0 && idx < s1) ? Y[idx] : -INFINITY;
    }
    sort8(v);
    merge8into16(t, v);
  }
  merge_partner(t, 1);
  merge_partner(t, 2);
  merge_partner(t, 4);
  float wv[KPOOL], m = -INFINITY, s = 0.0f;
#pragma unroll
  for (int k = 0; k < KPOOL; ++k) { wv[k] = W[k]; m = fmaxf(m, wv[k]); }
#pragma unroll
  for (int k = 0; k < KPOOL; ++k) { wv[k] = expf(wv[k] - m); s += wv[k]; }
  const float inv = 1.0f / s;
  float res = 0.0f;
#pragma unroll
  for (int k = 0; k < KPOOL; ++k) {
    const float tv = t[k];
    res += (tv > -INFINITY) ? tv * (wv[k] * inv) : 0.0f;
  }
  if (q == 0) out[g] = res;
}

extern "C" void kernel_launch(void* const* d_in, const int* in_sizes, int n_in,
                              void* d_out, int out_size, void* d_ws, size_t ws_size,
                              hipStream_t stream) {
  const float* Y = (const float*)d_in[0];   // [TOTAL]
  const float* W = (const float*)d_in[1];   // [16]
  const int* emap = (const int*)d_in[2];    // [TOTAL], sorted
  const int total = in_sizes[0];
  const int n = in_sizes[3];                // len(v_count)
  float* out = (float*)d_out;               // [N] float32

  int* starts = (int*)d_ws;
  float* wn_buf = (float*)((char*)d_ws + (size_t)(n + 1) * sizeof(int));
  const bool use_ws =
      (ws_size >= (size_t)(n + 1) * sizeof(int) + KPOOL * sizeof(float));

  if (use_ws) {
    const int nb = (n + 1 + 255) / 256;
    boundary_kernel<<<nb, 256, 0, stream>>>(emap, total, n, starts, wn_buf, W);
    const int blocks = (n + WPB * GPW - 1) / (WPB * GPW);
    sortpool_lds<<<blocks, 256, 0, stream>>>(Y, starts, wn_buf, out, total, n);
  } else {
    long long threads = (long long)n * SPLIT;
    const int blocks = (int)((threads + 255) / 256);
    sortpool_main_nows<<<blocks, 256, 0, stream>>>(Y, W, emap, out, total, n);
  }
}

// Round 16
// 36.557 us; speedup vs baseline: 1.2358x; 1.1539x over previous
//
#include <hip/hip_runtime.h>
#include <math.h>

#define KPOOL 16
#define SPLIT 8            // threads per graph; stream <= 6 batches (8 sigma)

typedef float f32x4 __attribute__((ext_vector_type(4)));

__device__ __forceinline__ void ce(float& x, float& y) {
  float hi = fmaxf(x, y), lo = fminf(x, y);
  x = hi;
  y = lo;
}

// Batcher odd-even mergesort, 8 inputs, 19 CEs, descending.
__device__ __forceinline__ void sort8(float (&v)[8]) {
  ce(v[0], v[1]); ce(v[2], v[3]); ce(v[4], v[5]); ce(v[6], v[7]);
  ce(v[0], v[2]); ce(v[1], v[3]); ce(v[4], v[6]); ce(v[5], v[7]);
  ce(v[1], v[2]); ce(v[5], v[6]);
  ce(v[0], v[4]); ce(v[1], v[5]); ce(v[2], v[6]); ce(v[3], v[7]);
  ce(v[2], v[4]); ce(v[3], v[5]);
  ce(v[1], v[2]); ce(v[3], v[4]); ce(v[5], v[6]);
}

// t sorted-16 desc, b sorted-8 desc -> t = top-16 of union, sorted.
__device__ __forceinline__ void merge8into16(float (&t)[KPOOL], const float (&b)[8]) {
#pragma unroll
  for (int i = 8; i < 16; ++i) t[i] = fmaxf(t[i], b[15 - i]);
#pragma unroll
  for (int s = 8; s >= 1; s >>= 1) {
#pragma unroll
    for (int i = 0; i < 16; ++i)
      if ((i & s) == 0) ce(t[i], t[i + s]);
  }
}

// Merge this lane's sorted-16 with lane^dist's: top-16 of union.
__device__ __forceinline__ void merge_partner(float (&t)[KPOOL], int dist) {
  float c[KPOOL];
#pragma unroll
  for (int i = 0; i < KPOOL; ++i) {
    float o = __shfl_xor(t[KPOOL - 1 - i], dist);
    c[i] = fmaxf(t[i], o);
  }
#pragma unroll
  for (int s = 8; s >= 1; s >>= 1) {
#pragma unroll
    for (int i = 0; i < KPOOL; ++i)
      if ((i & s) == 0) ce(c[i], c[i + s]);
  }
#pragma unroll
  for (int i = 0; i < KPOOL; ++i) t[i] = c[i];
}

__device__ __forceinline__ int lb_range(const int* __restrict__ a, int lo,
                                        int hi, int key) {
  while (lo < hi) {
    int mid = (lo + hi) >> 1;
    if (a[mid] < key) lo = mid + 1;
    else hi = mid;
  }
  return lo;
}

// Exact lower_bound via batched 8-ary search (7 independent probes/round over
// a +-16384 = 8-sigma verified window; full-range fallback for exactness).
__global__ __launch_bounds__(256)
void boundary_kernel(const int* __restrict__ emap, int total, int n,
                     int* __restrict__ starts, float* __restrict__ wn_out,
                     const float* __restrict__ W) {
  const int g = blockIdx.x * 256 + threadIdx.x;
  if (g == 0) {  // softmax(W), grid-uniform
    float w[KPOOL], m = -INFINITY, s = 0.0f;
#pragma unroll
    for (int k = 0; k < KPOOL; ++k) { w[k] = W[k]; m = fmaxf(m, w[k]); }
#pragma unroll
    for (int k = 0; k < KPOOL; ++k) { w[k] = expf(w[k] - m); s += w[k]; }
#pragma unroll
    for (int k = 0; k < KPOOL; ++k) wn_out[k] = w[k] / s;
  }
  if (g > n) return;
  if (g == 0) { starts[0] = 0; return; }       // e_map values >= 0
  if (g >= n) { starts[n] = total; return; }   // e_map values < n

  const int key = g;
  const int W0 = 32768;
  if (total < W0) { starts[g] = lb_range(emap, 0, total, key); return; }

  long long E = (long long)key * total / n;
  int wlo = (int)(E - W0 / 2);
  if (wlo < 0) wlo = 0;
  if (wlo > total - W0) wlo = total - W0;

  int p[7];
#pragma unroll
  for (int k = 0; k < 7; ++k) p[k] = emap[wlo + (k + 1) * 4096];
  const int vlo = (wlo > 0) ? emap[wlo - 1] : key - 1 - key;  // force "< key"
  const int vhi = emap[wlo + W0 - 1];
  const bool ok = (vlo < key) && ((wlo + W0 == total) || (vhi >= key));
  if (!ok) { starts[g] = lb_range(emap, 0, total, key); return; }

  int lo = wlo;
  int c = 0;
#pragma unroll
  for (int k = 0; k < 7; ++k) c += (p[k] < key) ? 1 : 0;
  lo += c * 4096;

#pragma unroll
  for (int w8 = 512; w8 >= 1; w8 >>= 3) {
#pragma unroll
    for (int k = 0; k < 7; ++k) p[k] = emap[lo + (k + 1) * w8];
    c = 0;
#pragma unroll
    for (int k = 0; k < 7; ++k) c += (p[k] < key) ? 1 : 0;
    lo += c * w8;
  }
  starts[g] = (emap[lo] < key) ? lo + 1 : lo;
}

// Consume one preloaded batch: mask (1 unsigned cmp/elem, interior skips),
// sort, merge. Compute-only condition; the LOAD was already issued upfront.
#define CONSUME(Va, Vb, bb)                                                \
  if ((bb) < B1) {                                                         \
    float v[8] = {Va[0], Va[1], Va[2], Va[3], Vb[0], Vb[1], Vb[2], Vb[3]}; \
    const int base_ = (bb) << 3;                                           \
    if (base_ < s0 || base_ + 8 > s1) {                                    \
      _Pragma("unroll") for (int jj = 0; jj < 8; ++jj) {                   \
        if ((unsigned)(base_ + jj - s0) >= ulen) v[jj] = -INFINITY;        \
      }                                                                    \
    }                                                                      \
    sort8(v);                                                              \
    merge8into16(t, v);                                                    \
  }

__global__ __launch_bounds__(256, 4)
void sortpool_main(const float* __restrict__ Y,
                   const int* __restrict__ starts,
                   const float* __restrict__ Wn,
                   float* __restrict__ out, int total, int n) {
  const int tid = blockIdx.x * 256 + threadIdx.x;
  const int g = tid >> 3;  // graph id; 8 consecutive lanes share a graph
  const int q = tid & 7;   // stride id
  if (g >= n) return;

  const int s0 = starts[g];
  const int s1 = starts[g + 1];
  const unsigned ulen = (unsigned)(s1 - s0);

  const int B0 = s0 >> 3;
  const int B1 = (s1 + 7) >> 3;
  const int lastB = (total >> 3) - 1;
  const int b0 = B0 + q;

  // ---- issue ALL stream loads upfront, unconditional, clamped in-bounds ----
  // (straight-line; consume order == issue order -> partial vmcnt waits)
  const int c0 = b0 <= lastB ? b0 : lastB;
  const int c1 = b0 + 1 * SPLIT <= lastB ? b0 + 1 * SPLIT : lastB;
  const int c2 = b0 + 2 * SPLIT <= lastB ? b0 + 2 * SPLIT : lastB;
  const int c3 = b0 + 3 * SPLIT <= lastB ? b0 + 3 * SPLIT : lastB;
  const int c4 = b0 + 4 * SPLIT <= lastB ? b0 + 4 * SPLIT : lastB;
  const int c5 = b0 + 5 * SPLIT <= lastB ? b0 + 5 * SPLIT : lastB;
  const f32x4* p0 = reinterpret_cast<const f32x4*>(Y + (c0 << 3));
  const f32x4* p1 = reinterpret_cast<const f32x4*>(Y + (c1 << 3));
  const f32x4* p2 = reinterpret_cast<const f32x4*>(Y + (c2 << 3));
  const f32x4* p3 = reinterpret_cast<const f32x4*>(Y + (c3 << 3));
  const f32x4* p4 = reinterpret_cast<const f32x4*>(Y + (c4 << 3));
  const f32x4* p5 = reinterpret_cast<const f32x4*>(Y + (c5 << 3));
  f32x4 v0a = p0[0], v0b = p0[1];
  f32x4 v1a = p1[0], v1b = p1[1];
  f32x4 v2a = p2[0], v2b = p2[1];
  f32x4 v3a = p3[0], v3b = p3[1];
  f32x4 v4a = p4[0], v4b = p4[1];
  f32x4 v5a = p5[0], v5b = p5[1];
  __builtin_amdgcn_sched_barrier(0);  // pin the issue cluster above consumes

  float t[KPOOL];
#pragma unroll
  for (int i = 0; i < KPOOL; ++i) t[i] = -INFINITY;

  CONSUME(v0a, v0b, b0)
  CONSUME(v1a, v1b, b0 + 1 * SPLIT)
  CONSUME(v2a, v2b, b0 + 2 * SPLIT)
  CONSUME(v3a, v3b, b0 + 3 * SPLIT)
  CONSUME(v4a, v4b, b0 + 4 * SPLIT)
  CONSUME(v5a, v5b, b0 + 5 * SPLIT)

  // exactness tail: streams longer than 6 batches (P ~ 1e-15 at Poisson(256))
#pragma unroll 1
  for (int b = b0 + 6 * SPLIT; b < B1; b += SPLIT) {
    const int cb = b <= lastB ? b : lastB;
    const f32x4* p = reinterpret_cast<const f32x4*>(Y + (cb << 3));
    const f32x4 a = p[0], d = p[1];
    float v[8] = {a[0], a[1], a[2], a[3], d[0], d[1], d[2], d[3]};
    const int base_ = b << 3;
#pragma unroll
    for (int jj = 0; jj < 8; ++jj)
      if ((unsigned)(base_ + jj - s0) >= ulen) v[jj] = -INFINITY;
    sort8(v);
    merge8into16(t, v);
  }

  // combine the 8 strides' sorted-16 lists (butterfly; all lanes equal)
  merge_partner(t, 1);
  merge_partner(t, 2);
  merge_partner(t, 4);

  // weighted sum with precomputed softmax(W); -inf slots (exhausted) -> 0
  float res = 0.0f;
#pragma unroll
  for (int k = 0; k < KPOOL; ++k) {
    const float tv = t[k];
    res += (tv > -INFINITY) ? tv * Wn[k] : 0.0f;
  }

  if (q == 0) out[g] = res;
}

// Fallback main (no workspace): per-thread full binary search, simple scan.
__global__ __launch_bounds__(256, 4)
void sortpool_main_nows(const float* __restrict__ Y, const float* __restrict__ W,
                        const int* __restrict__ emap, float* __restrict__ out,
                        int total, int n) {
  const int tid = blockIdx.x * 256 + threadIdx.x;
  const int g = tid >> 3;
  const int q = tid & 7;
  if (g >= n) return;
  const int s0 = lb_range(emap, 0, total, g);
  const int s1 = lb_range(emap, 0, total, g + 1);
  const unsigned ulen = (unsigned)(s1 - s0);
  const int B0 = s0 >> 3;
  const int B1 = (s1 + 7) >> 3;
  const int lastB = (total >> 3) - 1;
  float t[KPOOL];
#pragma unroll
  for (int i = 0; i < KPOOL; ++i) t[i] = -INFINITY;
#pragma unroll 1
  for (int b = B0 + q; b < B1; b += SPLIT) {
    const int cb = b <= lastB ? b : lastB;
    const f32x4* p = reinterpret_cast<const f32x4*>(Y + (cb << 3));
    const f32x4 a = p[0], d = p[1];
    float v[8] = {a[0], a[1], a[2], a[3], d[0], d[1], d[2], d[3]};
    const int base_ = b << 3;
#pragma unroll
    for (int jj = 0; jj < 8; ++jj)
      if ((unsigned)(base_ + jj - s0) >= ulen) v[jj] = -INFINITY;
    sort8(v);
    merge8into16(t, v);
  }
  merge_partner(t, 1);
  merge_partner(t, 2);
  merge_partner(t, 4);
  float wv[KPOOL], m = -INFINITY, s = 0.0f;
#pragma unroll
  for (int k = 0; k < KPOOL; ++k) { wv[k] = W[k]; m = fmaxf(m, wv[k]); }
#pragma unroll
  for (int k = 0; k < KPOOL; ++k) { wv[k] = expf(wv[k] - m); s += wv[k]; }
  const float inv = 1.0f / s;
  float res = 0.0f;
#pragma unroll
  for (int k = 0; k < KPOOL; ++k) {
    const float tv = t[k];
    res += (tv > -INFINITY) ? tv * (wv[k] * inv) : 0.0f;
  }
  if (q == 0) out[g] = res;
}

extern "C" void kernel_launch(void* const* d_in, const int* in_sizes, int n_in,
                              void* d_out, int out_size, void* d_ws, size_t ws_size,
                              hipStream_t stream) {
  const float* Y = (const float*)d_in[0];   // [TOTAL]
  const float* W = (const float*)d_in[1];   // [16]
  const int* emap = (const int*)d_in[2];    // [TOTAL], sorted
  const int total = in_sizes[0];
  const int n = in_sizes[3];                // len(v_count)
  float* out = (float*)d_out;               // [N] float32

  int* starts = (int*)d_ws;
  float* wn_buf = (float*)((char*)d_ws + (size_t)(n + 1) * sizeof(int));
  const bool use_ws =
      (ws_size >= (size_t)(n + 1) * sizeof(int) + KPOOL * sizeof(float));

  long long threads = (long long)n * SPLIT;
  const int blocks = (int)((threads + 255) / 256);

  if (use_ws) {
    const int nb = (n + 1 + 255) / 256;
    boundary_kernel<<<nb, 256, 0, stream>>>(emap, total, n, starts, wn_buf, W);
    sortpool_main<<<blocks, 256, 0, stream>>>(Y, starts, wn_buf, out, total, n);
  } else {
    sortpool_main_nows<<<blocks, 256, 0, stream>>>(Y, W, emap, out, total, n);
  }
}

// Round 17
// 35.951 us; speedup vs baseline: 1.2566x; 1.0168x over previous
//
#include <hip/hip_runtime.h>
#include <math.h>

#define KPOOL 16
#define SPLIT 8            // threads per graph; stream <= 6 batches (+8 sigma)

typedef float f32x4 __attribute__((ext_vector_type(4)));

__device__ __forceinline__ void ce(float& x, float& y) {
  float hi = fmaxf(x, y), lo = fminf(x, y);
  x = hi;
  y = lo;
}

// Batcher odd-even mergesort, 8 inputs, 19 CEs, descending.
__device__ __forceinline__ void sort8(float (&v)[8]) {
  ce(v[0], v[1]); ce(v[2], v[3]); ce(v[4], v[5]); ce(v[6], v[7]);
  ce(v[0], v[2]); ce(v[1], v[3]); ce(v[4], v[6]); ce(v[5], v[7]);
  ce(v[1], v[2]); ce(v[5], v[6]);
  ce(v[0], v[4]); ce(v[1], v[5]); ce(v[2], v[6]); ce(v[3], v[7]);
  ce(v[2], v[4]); ce(v[3], v[5]);
  ce(v[1], v[2]); ce(v[3], v[4]); ce(v[5], v[6]);
}

// t sorted-16 desc, b sorted-8 desc -> t = top-16 of union, sorted.
__device__ __forceinline__ void merge8into16(float (&t)[KPOOL], const float (&b)[8]) {
#pragma unroll
  for (int i = 8; i < 16; ++i) t[i] = fmaxf(t[i], b[15 - i]);
#pragma unroll
  for (int s = 8; s >= 1; s >>= 1) {
#pragma unroll
    for (int i = 0; i < 16; ++i)
      if ((i & s) == 0) ce(t[i], t[i + s]);
  }
}

// Merge this lane's sorted-16 with lane^dist's: top-16 of union.
__device__ __forceinline__ void merge_partner(float (&t)[KPOOL], int dist) {
  float c[KPOOL];
#pragma unroll
  for (int i = 0; i < KPOOL; ++i) {
    float o = __shfl_xor(t[KPOOL - 1 - i], dist);
    c[i] = fmaxf(t[i], o);
  }
#pragma unroll
  for (int s = 8; s >= 1; s >>= 1) {
#pragma unroll
    for (int i = 0; i < KPOOL; ++i)
      if ((i & s) == 0) ce(c[i], c[i + s]);
  }
#pragma unroll
  for (int i = 0; i < KPOOL; ++i) t[i] = c[i];
}

__device__ __forceinline__ int lb_range(const int* __restrict__ a, int lo,
                                        int hi, int key) {
  while (lo < hi) {
    int mid = (lo + hi) >> 1;
    if (a[mid] < key) lo = mid + 1;
    else hi = mid;
  }
  return lo;
}

// Exact lower_bound via batched 8-ary search (7 independent probes/round over
// a +-16384 = 8-sigma verified window; full-range fallback for exactness).
__global__ __launch_bounds__(256)
void boundary_kernel(const int* __restrict__ emap, int total, int n,
                     int* __restrict__ starts, float* __restrict__ wn_out,
                     const float* __restrict__ W) {
  const int g = blockIdx.x * 256 + threadIdx.x;
  if (g == 0) {  // softmax(W), grid-uniform
    float w[KPOOL], m = -INFINITY, s = 0.0f;
#pragma unroll
    for (int k = 0; k < KPOOL; ++k) { w[k] = W[k]; m = fmaxf(m, w[k]); }
#pragma unroll
    for (int k = 0; k < KPOOL; ++k) { w[k] = expf(w[k] - m); s += w[k]; }
#pragma unroll
    for (int k = 0; k < KPOOL; ++k) wn_out[k] = w[k] / s;
  }
  if (g > n) return;
  if (g == 0) { starts[0] = 0; return; }       // e_map values >= 0
  if (g >= n) { starts[n] = total; return; }   // e_map values < n

  const int key = g;
  const int W0 = 32768;
  if (total < W0) { starts[g] = lb_range(emap, 0, total, key); return; }

  long long E = (long long)key * total / n;
  int wlo = (int)(E - W0 / 2);
  if (wlo < 0) wlo = 0;
  if (wlo > total - W0) wlo = total - W0;

  int p[7];
#pragma unroll
  for (int k = 0; k < 7; ++k) p[k] = emap[wlo + (k + 1) * 4096];
  const int vlo = (wlo > 0) ? emap[wlo - 1] : key - 1 - key;  // force "< key"
  const int vhi = emap[wlo + W0 - 1];
  const bool ok = (vlo < key) && ((wlo + W0 == total) || (vhi >= key));
  if (!ok) { starts[g] = lb_range(emap, 0, total, key); return; }

  int lo = wlo;
  int c = 0;
#pragma unroll
  for (int k = 0; k < 7; ++k) c += (p[k] < key) ? 1 : 0;
  lo += c * 4096;

#pragma unroll
  for (int w8 = 512; w8 >= 1; w8 >>= 3) {
#pragma unroll
    for (int k = 0; k < 7; ++k) p[k] = emap[lo + (k + 1) * w8];
    c = 0;
#pragma unroll
    for (int k = 0; k < 7; ++k) c += (p[k] < key) ? 1 : 0;
    lo += c * w8;
  }
  starts[g] = (emap[lo] < key) ? lo + 1 : lo;
}

// Inline-asm load: the compiler CANNOT sink/remat asm volatile, and must keep
// the "=&v" outputs live -> all 12 loads stay in flight (vmcnt FIFO order =
// program order of the volatile asm statements).
#define ALOAD(D0, D1, PTR)                                                  \
  asm volatile("global_load_dwordx4 %0, %2, off\n\t"                       \
               "global_load_dwordx4 %1, %2, off offset:16"                  \
               : "=&v"(D0), "=&v"(D1)                                       \
               : "v"(PTR)                                                   \
               : "memory");

// Wait until <=CNT of my asm loads remain outstanding, then consume batch bb.
// sched_barrier stops the scheduler hoisting the (register-only) consume code
// above the waitcnt (rule-18 fence).
#define CONSUME(CNT, Va, Vb, bb)                                            \
  asm volatile("s_waitcnt vmcnt(" #CNT ")" ::: "memory");                   \
  __builtin_amdgcn_sched_barrier(0);                                        \
  if ((bb) < B1) {                                                          \
    float v[8] = {Va[0], Va[1], Va[2], Va[3], Vb[0], Vb[1], Vb[2], Vb[3]};  \
    const int base_ = (bb) << 3;                                            \
    if (base_ < s0 || base_ + 8 > s1) {                                     \
      _Pragma("unroll") for (int jj = 0; jj < 8; ++jj) {                    \
        if ((unsigned)(base_ + jj - s0) >= ulen) v[jj] = -INFINITY;         \
      }                                                                     \
    }                                                                       \
    sort8(v);                                                               \
    merge8into16(t, v);                                                     \
  }

__global__ __launch_bounds__(256, 4)
void sortpool_main(const float* __restrict__ Y,
                   const int* __restrict__ starts,
                   const float* __restrict__ Wn,
                   float* __restrict__ out, int total, int n) {
  const int tid = blockIdx.x * 256 + threadIdx.x;
  const int g = tid >> 3;  // graph id; 8 consecutive lanes share a graph
  const int q = tid & 7;   // stride id
  if (g >= n) return;

  const int s0 = starts[g];       // compiler waits these before addr use
  const int s1 = starts[g + 1];
  const unsigned ulen = (unsigned)(s1 - s0);

  const int B0 = s0 >> 3;
  const int B1 = (s1 + 7) >> 3;
  const int lastB = (total >> 3) - 1;
  const int b0 = B0 + q;

  // clamped in-bounds addresses for the 6-batch stream
  const int c0 = b0 <= lastB ? b0 : lastB;
  const int c1 = b0 + 1 * SPLIT <= lastB ? b0 + 1 * SPLIT : lastB;
  const int c2 = b0 + 2 * SPLIT <= lastB ? b0 + 2 * SPLIT : lastB;
  const int c3 = b0 + 3 * SPLIT <= lastB ? b0 + 3 * SPLIT : lastB;
  const int c4 = b0 + 4 * SPLIT <= lastB ? b0 + 4 * SPLIT : lastB;
  const int c5 = b0 + 5 * SPLIT <= lastB ? b0 + 5 * SPLIT : lastB;

  // ---- issue ALL 12 dwordx4 loads via asm (12 outstanding, FIFO) ----
  f32x4 v0a, v0b, v1a, v1b, v2a, v2b, v3a, v3b, v4a, v4b, v5a, v5b;
  ALOAD(v0a, v0b, Y + (c0 << 3));
  ALOAD(v1a, v1b, Y + (c1 << 3));
  ALOAD(v2a, v2b, Y + (c2 << 3));
  ALOAD(v3a, v3b, Y + (c3 << 3));
  ALOAD(v4a, v4b, Y + (c4 << 3));
  ALOAD(v5a, v5b, Y + (c5 << 3));

  float t[KPOOL];
#pragma unroll
  for (int i = 0; i < KPOOL; ++i) t[i] = -INFINITY;

  // staged partial waits: one exposed latency, the rest pipeline behind it
  CONSUME(10, v0a, v0b, b0)
  CONSUME(8, v1a, v1b, b0 + 1 * SPLIT)
  CONSUME(6, v2a, v2b, b0 + 2 * SPLIT)
  CONSUME(4, v3a, v3b, b0 + 3 * SPLIT)
  CONSUME(2, v4a, v4b, b0 + 4 * SPLIT)
  CONSUME(0, v5a, v5b, b0 + 5 * SPLIT)

  // exactness tail: streams >6 batches (P ~ 1e-15); plain C++ (over-waits ok)
#pragma unroll 1
  for (int b = b0 + 6 * SPLIT; b < B1; b += SPLIT) {
    const int cb = b <= lastB ? b : lastB;
    const f32x4* p = reinterpret_cast<const f32x4*>(Y + (cb << 3));
    const f32x4 a = p[0], d = p[1];
    float v[8] = {a[0], a[1], a[2], a[3], d[0], d[1], d[2], d[3]};
    const int base_ = b << 3;
#pragma unroll
    for (int jj = 0; jj < 8; ++jj)
      if ((unsigned)(base_ + jj - s0) >= ulen) v[jj] = -INFINITY;
    sort8(v);
    merge8into16(t, v);
  }

  // combine the 8 strides' sorted-16 lists (butterfly; all lanes equal)
  merge_partner(t, 1);
  merge_partner(t, 2);
  merge_partner(t, 4);

  // weighted sum with precomputed softmax(W); -inf slots (exhausted) -> 0
  float res = 0.0f;
#pragma unroll
  for (int k = 0; k < KPOOL; ++k) {
    const float tv = t[k];
    res += (tv > -INFINITY) ? tv * Wn[k] : 0.0f;
  }

  if (q == 0) out[g] = res;
}

// Fallback main (no workspace): per-thread full binary search, simple scan.
__global__ __launch_bounds__(256, 4)
void sortpool_main_nows(const float* __restrict__ Y, const float* __restrict__ W,
                        const int* __restrict__ emap, float* __restrict__ out,
                        int total, int n) {
  const int tid = blockIdx.x * 256 + threadIdx.x;
  const int g = tid >> 3;
  const int q = tid & 7;
  if (g >= n) return;
  const int s0 = lb_range(emap, 0, total, g);
  const int s1 = lb_range(emap, 0, total, g + 1);
  const unsigned ulen = (unsigned)(s1 - s0);
  const int B0 = s0 >> 3;
  const int B1 = (s1 + 7) >> 3;
  const int lastB = (total >> 3) - 1;
  float t[KPOOL];
#pragma unroll
  for (int i = 0; i < KPOOL; ++i) t[i] = -INFINITY;
#pragma unroll 1
  for (int b = B0 + q; b < B1; b += SPLIT) {
    const int cb = b <= lastB ? b : lastB;
    const f32x4* p = reinterpret_cast<const f32x4*>(Y + (cb << 3));
    const f32x4 a = p[0], d = p[1];
    float v[8] = {a[0], a[1], a[2], a[3], d[0], d[1], d[2], d[3]};
    const int base_ = b << 3;
#pragma unroll
    for (int jj = 0; jj < 8; ++jj)
      if ((unsigned)(base_ + jj - s0) >= ulen) v[jj] = -INFINITY;
    sort8(v);
    merge8into16(t, v);
  }
  merge_partner(t, 1);
  merge_partner(t, 2);
  merge_partner(t, 4);
  float wv[KPOOL], m = -INFINITY, s = 0.0f;
#pragma unroll
  for (int k = 0; k < KPOOL; ++k) { wv[k] = W[k]; m = fmaxf(m, wv[k]); }
#pragma unroll
  for (int k = 0; k < KPOOL; ++k) { wv[k] = expf(wv[k] - m); s += wv[k]; }
  const float inv = 1.0f / s;
  float res = 0.0f;
#pragma unroll
  for (int k = 0; k < KPOOL; ++k) {
    const float tv = t[k];
    res += (tv > -INFINITY) ? tv * (wv[k] * inv) : 0.0f;
  }
  if (q == 0) out[g] = res;
}

extern "C" void kernel_launch(void* const* d_in, const int* in_sizes, int n_in,
                              void* d_out, int out_size, void* d_ws, size_t ws_size,
                              hipStream_t stream) {
  const float* Y = (const float*)d_in[0];   // [TOTAL]
  const float* W = (const float*)d_in[1];   // [16]
  const int* emap = (const int*)d_in[2];    // [TOTAL], sorted
  const int total = in_sizes[0];
  const int n = in_sizes[3];                // len(v_count)
  float* out = (float*)d_out;               // [N] float32

  int* starts = (int*)d_ws;
  float* wn_buf = (float*)((char*)d_ws + (size_t)(n + 1) * sizeof(int));
  const bool use_ws =
      (ws_size >= (size_t)(n + 1) * sizeof(int) + KPOOL * sizeof(float));

  long long threads = (long long)n * SPLIT;
  const int blocks = (int)((threads + 255) / 256);

  if (use_ws) {
    const int nb = (n + 1 + 255) / 256;
    boundary_kernel<<<nb, 256, 0, stream>>>(emap, total, n, starts, wn_buf, W);
    sortpool_main<<<blocks, 256, 0, stream>>>(Y, starts, wn_buf, out, total, n);
  } else {
    sortpool_main_nows<<<blocks, 256, 0, stream>>>(Y, W, emap, out, total, n);
  }
}